// Round 15
// baseline (152.621 us; speedup 1.0000x reference)
//
#include <hip/hip_runtime.h>

#define DEVINL __device__ __forceinline__

typedef __attribute__((ext_vector_type(8))) _Float16 h8v;         // 8 fp16 (MFMA operand)
typedef __attribute__((ext_vector_type(4))) float f32x4;
typedef __attribute__((ext_vector_type(8))) unsigned short us8;
typedef __attribute__((ext_vector_type(4))) unsigned short us4;

DEVINL unsigned short f2h(float f) {                  // fp32 -> fp16 bits (RTE)
  return __builtin_bit_cast(unsigned short, (_Float16)f);
}
DEVINL float h2f(unsigned short u) {
  return (float)__builtin_bit_cast(_Float16, u);
}

#if __has_builtin(__builtin_amdgcn_global_load_lds)
#define HAVE_GLOAD_LDS 1
#else
#define HAVE_GLOAD_LDS 0
#endif

// ------------------------------------------------------------------
// weights (row-major): wall_h rows [0..127]=theta, [128..255]=phi,
// [256..383]=g; wall_l = fp16 residual rows 0..255; W2 fp16 [256][128]
// ------------------------------------------------------------------
__global__ __launch_bounds__(256)
void prep_weights(const float* __restrict__ g_w, const float* __restrict__ th_w,
                  const float* __restrict__ ph_w, const float* __restrict__ W_w,
                  unsigned short* __restrict__ wall_h, unsigned short* __restrict__ wall_l,
                  unsigned short* __restrict__ w2h)
{
  const int i = blockIdx.x * 256 + threadIdx.x;  // [0, 98304)
  float v;
  if (i < 32768) v = th_w[i];
  else if (i < 65536) v = ph_w[i - 32768];
  else v = g_w[i - 65536];
  const unsigned short h = f2h(v);
  wall_h[i] = h;
  if (i < 65536) wall_l[i] = f2h(v - h2f(h));
  if (i < 32768) w2h[i] = f2h(W_w[i]);
}

// ------------------------------------------------------------------
// Fused projection, tile = M384 x N128, BK=32, FULLY DOUBLE-BUFFERED
// single-barrier pipeline (T3-minimum):
//   per kt: issue gload_lds A(kt+1)->buf^1 (async, 0 VGPR);
//           convert x(kt+1) (regs, loaded 2 intervals ago) -> Bs[buf^1];
//           issue x(kt+2) loads -> alternate reg set;
//           MFMA(kt) on buf;  ONE __syncthreads (vmcnt+lgkm drain
//           happens UNDER the MFMA phase, not serial after it).
// LDS: 2 x (As_h 384x40 + As_l 256x40) + 2 x (Bs_h/Bs_l 128x40)
//    = 71,680 shorts = 140KB (1 blk/CU, 8 waves).  Pitch 40 shorts
//    = 80B rows: 16B-aligned, 2-way bank (free).
// MFMA accumulation order over 32-k chunks identical to r13 (BK=64
// had two 32-k sub-steps) -> bit-identical z -> absmax unchanged.
// theta/phi rows: 3-pass fp16 hi/lo split; g rows: 1-pass.
// Epilogue: r3-style direct (fp32 zr + fp16 zg) + stats partials.
// ------------------------------------------------------------------
__global__ __launch_bounds__(512)
void proj_gemm(const unsigned short* __restrict__ wall_h,
               const unsigned short* __restrict__ wall_l,
               const float* __restrict__ x,
               float* __restrict__ zr, unsigned short* __restrict__ zg,
               float* __restrict__ partials)
{
  // [A buf0: 25600][A buf1: 25600][B buf0: 10240][B buf1: 10240]
  __shared__ __align__(16) unsigned short smem[71680];

  const int t = threadIdx.x;
  const int lane = t & 63;
  const int wave = t >> 6;                 // 0..7
  const int wm = wave >> 1, wn = wave & 1; // 4 x 2
  const int lr = lane & 15, lk = lane >> 4;
  const int b = blockIdx.z;
  const int bx = blockIdx.x;
  const int nbase = bx * 128;
  const float* xs = x + (long)b * 256 * 4096;

  f32x4 acc[6][4];
#pragma unroll
  for (int i = 0; i < 6; ++i)
#pragma unroll
    for (int j = 0; j < 4; ++j) acc[i][j] = (f32x4)0.0f;

  const int nl = t & 127, cg = t >> 7;     // B: lane-per-n, cg covers 8 k each

  float xva[8], xvb[8];

  // ---------- A stage (async gload_lds or sync fallback) ----------
#if HAVE_GLOAD_LDS
#define GLOAD_A(K0, BUF)                                                         \
  do {                                                                           \
    unsigned short* dsth_ = smem + (BUF) * 25600;                                \
    unsigned short* dstl_ = dsth_ + 15360;                                       \
    _Pragma("unroll")                                                            \
    for (int i_ = 0; i_ < 4; ++i_) {                                             \
      const int ch = i_ * 8 + wave;                                              \
      if (ch < 30) {                                                             \
        const int s = ch * 512 + (lane << 3);                                    \
        const int row = s / 40;                                                  \
        const int c8 = (s - row * 40) >> 3;                                      \
        const unsigned short* src =                                              \
            (c8 < 4) ? &wall_h[(long)row * 256 + (K0) + c8 * 8] : wall_h;        \
        __builtin_amdgcn_global_load_lds(                                        \
            (const __attribute__((address_space(1))) unsigned int*)src,          \
            (__attribute__((address_space(3))) unsigned int*)&dsth_[ch * 512],   \
            16, 0, 0);                                                           \
      }                                                                          \
    }                                                                            \
    _Pragma("unroll")                                                            \
    for (int i_ = 0; i_ < 3; ++i_) {                                             \
      const int ch = i_ * 8 + wave;                                              \
      if (ch < 20) {                                                             \
        const int s = ch * 512 + (lane << 3);                                    \
        const int row = s / 40;                                                  \
        const int c8 = (s - row * 40) >> 3;                                      \
        const unsigned short* src =                                              \
            (c8 < 4) ? &wall_l[(long)row * 256 + (K0) + c8 * 8] : wall_l;        \
        __builtin_amdgcn_global_load_lds(                                        \
            (const __attribute__((address_space(1))) unsigned int*)src,          \
            (__attribute__((address_space(3))) unsigned int*)&dstl_[ch * 512],   \
            16, 0, 0);                                                           \
      }                                                                          \
    }                                                                            \
  } while (0)
#else
#define GLOAD_A(K0, BUF)                                                         \
  do {                                                                           \
    unsigned short* dsth_ = smem + (BUF) * 25600;                                \
    unsigned short* dstl_ = dsth_ + 15360;                                       \
    _Pragma("unroll")                                                            \
    for (int i_ = 0; i_ < 3; ++i_) {                                             \
      const int q = i_ * 512 + t;                                                \
      const int row = q >> 2, c = q & 3;                                         \
      *(us8*)&dsth_[row * 40 + c * 8] =                                          \
          *(const us8*)&wall_h[(long)row * 256 + (K0) + c * 8];                  \
    }                                                                            \
    _Pragma("unroll")                                                            \
    for (int i_ = 0; i_ < 2; ++i_) {                                             \
      const int q = i_ * 512 + t;                                                \
      const int row = q >> 2, c = q & 3;                                         \
      *(us8*)&dstl_[row * 40 + c * 8] =                                          \
          *(const us8*)&wall_l[(long)row * 256 + (K0) + c * 8];                  \
    }                                                                            \
  } while (0)
#endif

#define LOAD_X(K0, XV)                                                           \
  _Pragma("unroll")                                                              \
  for (int i_ = 0; i_ < 8; ++i_)                                                 \
    XV[i_] = xs[(long)((K0) + cg * 8 + i_) * 4096 + nbase + nl];

#define CONV_WRITE_B(XV, BUF)                                                    \
  do {                                                                           \
    unsigned short* bh_ = smem + 51200 + (BUF) * 10240;                          \
    unsigned short* bl_ = bh_ + 5120;                                            \
    us8 h8_, l8_;                                                                \
    _Pragma("unroll")                                                            \
    for (int e = 0; e < 8; ++e) {                                                \
      const float v_ = XV[e];                                                    \
      const unsigned short hb_ = f2h(v_);                                        \
      h8_[e] = hb_;                                                              \
      l8_[e] = f2h(v_ - h2f(hb_));                                               \
    }                                                                            \
    *(us8*)&bh_[nl * 40 + cg * 8] = h8_;                                         \
    *(us8*)&bl_[nl * 40 + cg * 8] = l8_;                                         \
  } while (0)

  // ---- prologue: stage kt=0, preload x(1) ----
  LOAD_X(0, xva);
  GLOAD_A(0, 0);
  CONV_WRITE_B(xva, 0);
  LOAD_X(32, xvb);
  __syncthreads();

#pragma unroll
  for (int kt = 0; kt < 8; ++kt) {
    const int cur = kt & 1, nxt = cur ^ 1;
    if (kt < 7) GLOAD_A((kt + 1) * 32, nxt);
    if (kt & 1) {
      if (kt < 7) CONV_WRITE_B(xva, nxt);
      if (kt < 6) LOAD_X((kt + 2) * 32, xvb);
    } else {
      if (kt < 7) CONV_WRITE_B(xvb, nxt);
      if (kt < 6) LOAD_X((kt + 2) * 32, xva);
    }

    // MFMA(kt) on buffer `cur`
    {
      const unsigned short* Ah = smem + cur * 25600;
      const unsigned short* Al = Ah + 15360;
      const unsigned short* Bh = smem + 51200 + cur * 10240;
      const unsigned short* Bl = Bh + 5120;
      const int ko = lk * 8;
      h8v bh[4], bl[4];
#pragma unroll
      for (int ni = 0; ni < 4; ++ni) {
        const int r = (wn * 64 + ni * 16 + lr) * 40 + ko;
        bh[ni] = *(const h8v*)&Bh[r];
        bl[ni] = *(const h8v*)&Bl[r];
      }
#pragma unroll
      for (int mi = 0; mi < 6; ++mi) {
        const int fr = mi * 4 + wm;        // frag row block 0..23
        const h8v ah = *(const h8v*)&Ah[(fr * 16 + lr) * 40 + ko];
        if (fr < 16) {                      // theta/phi: 3-pass split
          const h8v al = *(const h8v*)&Al[(fr * 16 + lr) * 40 + ko];
#pragma unroll
          for (int ni = 0; ni < 4; ++ni) {
            acc[mi][ni] = __builtin_amdgcn_mfma_f32_16x16x32_f16(bh[ni], ah, acc[mi][ni], 0, 0, 0);
            acc[mi][ni] = __builtin_amdgcn_mfma_f32_16x16x32_f16(bl[ni], ah, acc[mi][ni], 0, 0, 0);
            acc[mi][ni] = __builtin_amdgcn_mfma_f32_16x16x32_f16(bh[ni], al, acc[mi][ni], 0, 0, 0);
          }
        } else {                            // g: 1-pass
#pragma unroll
          for (int ni = 0; ni < 4; ++ni)
            acc[mi][ni] = __builtin_amdgcn_mfma_f32_16x16x32_f16(bh[ni], ah, acc[mi][ni], 0, 0, 0);
        }
      }
    }
    __syncthreads();
  }

  // ---- partial stats: per row m, sum over this block's 128 n ----
  float* sbuf = (float*)smem;              // 6144 floats = 24KB alias
#pragma unroll
  for (int mi = 0; mi < 6; ++mi) {
    float s = 0.f, ss = 0.f;
#pragma unroll
    for (int ni = 0; ni < 4; ++ni)
#pragma unroll
      for (int r = 0; r < 4; ++r) {
        const float v = acc[mi][ni][r];
        s += v; ss += v * v;
      }
    const int fr = mi * 4 + wm;
    const int slot = ((fr * 16 + lr) * 8 + (wn * 4 + lk)) * 2;
    sbuf[slot] = s; sbuf[slot + 1] = ss;
  }
  __syncthreads();
  if (t < 384) {
    float s = 0.f, ss = 0.f;
#pragma unroll
    for (int w = 0; w < 8; ++w) {
      s += sbuf[(t * 8 + w) * 2];
      ss += sbuf[(t * 8 + w) * 2 + 1];
    }
    const long pidx = ((long)bx * 6144 + b * 384 + t) * 2;
    partials[pidx] = s; partials[pidx + 1] = ss;
  }

  // ---- C write (r3-style direct): theta/phi -> fp32 zr; g -> fp16 zg ----
#pragma unroll
  for (int mi = 0; mi < 6; ++mi)
#pragma unroll
    for (int ni = 0; ni < 4; ++ni) {
      const int gm = (mi * 4 + wm) * 16 + lr;
      const int gn = nbase + wn * 64 + ni * 16 + lk * 4;
      if (mi < 4) {
        *(f32x4*)&zr[((long)b * 256 + gm) * 4096 + gn] = acc[mi][ni];
      } else {
        us4 hv;
#pragma unroll
        for (int r = 0; r < 4; ++r) hv[r] = f2h(acc[mi][ni][r]);
        *(us4*)&zg[((long)b * 128 + (gm - 256)) * 4096 + gn] = hv;
      }
    }
#undef GLOAD_A
#undef LOAD_X
#undef CONV_WRITE_B
}

// ------------------------------------------------------------------
// reduce 32 partial (s,ss) per row -> stats[row] = {rs, -mean*rs}
// ------------------------------------------------------------------
__global__ __launch_bounds__(256)
void stats_reduce(const float* __restrict__ partials, float* __restrict__ stats)
{
  const int row = blockIdx.x * 256 + threadIdx.x;   // [0, 6144)
  float s = 0.f, ss = 0.f;
#pragma unroll
  for (int k = 0; k < 32; ++k) {
    s += partials[((long)k * 6144 + row) * 2];
    ss += partials[((long)k * 6144 + row) * 2 + 1];
  }
  const float mean = s * (1.f / 4096.f);
  const float var = ss * (1.f / 4096.f) - mean * mean;
  const float rs = rsqrtf(fmaxf(var, 0.f) + 1e-5f);
  stats[row * 2] = rs;
  stats[row * 2 + 1] = -mean * rs;
}

// ------------------------------------------------------------------
// f = theta.phi^T, 3-pass fp16 split; staging reads RAW FP32 zr,
// applies normalize+relu, splits hi/lo to LDS.  Tile 128x128, BK=64,
// K-slice 128 per z1 (32 chunks).
// ------------------------------------------------------------------
__global__ __launch_bounds__(256, 2)
void fgemm_norm(const float* __restrict__ zr,
                const float* __restrict__ stats, float* __restrict__ fpart)
{
  __shared__ __align__(16) unsigned short As_h[128 * 72];
  __shared__ __align__(16) unsigned short As_l[128 * 72];
  __shared__ __align__(16) unsigned short Bs_h[128 * 72];
  __shared__ __align__(16) unsigned short Bs_l[128 * 72];

  const int t = threadIdx.x;
  const int lane = t & 63;
  const int wave = t >> 6;
  const int wm = wave >> 1, wn = wave & 1;
  const int lr = lane & 15, lk = lane >> 4;
  const int zb = blockIdx.z >> 5, z1 = blockIdx.z & 31;
  const int koff = z1 * 128;

  f32x4 acc[4][4];
#pragma unroll
  for (int i = 0; i < 4; ++i)
#pragma unroll
    for (int j = 0; j < 4; ++j) acc[i][j] = (f32x4)0.0f;

  for (int kt = 0; kt < 2; ++kt) {
    const int k0 = koff + kt * 64;
#pragma unroll
    for (int i = 0; i < 4; ++i) {
      const int q = i * 256 + t;
      const int row = q >> 3, c = q & 7;
      // A = theta (zr rows 0..127), B = phi (zr rows 128..255)
#pragma unroll
      for (int op = 0; op < 2; ++op) {
        const int zrow = op * 128 + row;
        const float* src = zr + ((long)zb * 256 + zrow) * 4096 + k0 + c * 8;
        const f32x4 v0 = *(const f32x4*)&src[0];
        const f32x4 v1 = *(const f32x4*)&src[4];
        const int srow = zb * 384 + zrow;
        const float rs = stats[srow * 2];
        const float nmrs = stats[srow * 2 + 1];
        us8 oh, ol;
#pragma unroll
        for (int e = 0; e < 8; ++e) {
          const float v = (e < 4) ? v0[e] : v1[e - 4];
          const float nv = fmaxf(__builtin_fmaf(v, rs, nmrs), 0.f);
          const unsigned short hb = f2h(nv);
          oh[e] = hb;
          ol[e] = f2h(nv - h2f(hb));
        }
        unsigned short* dh = op ? Bs_h : As_h;
        unsigned short* dl = op ? Bs_l : As_l;
        *(us8*)&dh[row * 72 + c * 8] = oh;
        *(us8*)&dl[row * 72 + c * 8] = ol;
      }
    }
    __syncthreads();
#pragma unroll
    for (int ks = 0; ks < 2; ++ks) {
      const int ko = ks * 32 + lk * 8;
      h8v ah[4], bh[4], al[4], bl[4];
#pragma unroll
      for (int mi = 0; mi < 4; ++mi) {
        const int r = (wm * 64 + mi * 16 + lr) * 72 + ko;
        ah[mi] = *(const h8v*)&As_h[r];
        al[mi] = *(const h8v*)&As_l[r];
      }
#pragma unroll
      for (int ni = 0; ni < 4; ++ni) {
        const int r = (wn * 64 + ni * 16 + lr) * 72 + ko;
        bh[ni] = *(const h8v*)&Bs_h[r];
        bl[ni] = *(const h8v*)&Bs_l[r];
      }
#pragma unroll
      for (int mi = 0; mi < 4; ++mi)
#pragma unroll
        for (int ni = 0; ni < 4; ++ni) {
          acc[mi][ni] = __builtin_amdgcn_mfma_f32_16x16x32_f16(bh[ni], ah[mi], acc[mi][ni], 0, 0, 0);
          acc[mi][ni] = __builtin_amdgcn_mfma_f32_16x16x32_f16(bl[ni], ah[mi], acc[mi][ni], 0, 0, 0);
          acc[mi][ni] = __builtin_amdgcn_mfma_f32_16x16x32_f16(bh[ni], al[mi], acc[mi][ni], 0, 0, 0);
        }
    }
    __syncthreads();
  }

  const long cOff = ((long)zb * 32 + z1) * 16384;
#pragma unroll
  for (int mi = 0; mi < 4; ++mi)
#pragma unroll
    for (int ni = 0; ni < 4; ++ni) {
      const int gm = wm * 64 + mi * 16 + lr;
      const int gn = wn * 64 + ni * 16 + lk * 4;
      *(f32x4*)&fpart[cOff + (long)gm * 128 + gn] = acc[mi][ni];
    }
}

// ------------------------------------------------------------------
// y GEMM: tile 128x128, BK=64, fp16, LDS-bounce coalesced epilogue.
// ------------------------------------------------------------------
__global__ __launch_bounds__(256, 2)
void gemm_y(const unsigned short* __restrict__ Ah0, const unsigned short* __restrict__ Bh0,
            unsigned short* __restrict__ Cout,
            int lda, int ldb, int ldc, int ksteps, int z1count,
            long aS1, long aS2, long bS1, long bS2, long cS1, long cS2)
{
  __shared__ __align__(16) unsigned short smem[18432];   // As|Bs, reused as T
  unsigned short* As = smem;                 // 128*72
  unsigned short* Bs = smem + 9216;          // 128*72

  const int t = threadIdx.x;
  const int lane = t & 63;
  const int wave = t >> 6;
  const int wm = wave >> 1, wn = wave & 1;
  const int lr = lane & 15, lk = lane >> 4;

  const int z = blockIdx.z;
  const int zb = z / z1count, z1 = z - zb * z1count;
  const unsigned short* Ah = Ah0 + zb * aS2 + z1 * aS1;
  const unsigned short* Bh = Bh0 + zb * bS2 + z1 * bS1;
  const long cOff = zb * cS2 + z1 * cS1;

  f32x4 acc[4][4];
#pragma unroll
  for (int i = 0; i < 4; ++i)
#pragma unroll
    for (int j = 0; j < 4; ++j) acc[i][j] = (f32x4)0.0f;

  for (int kt = 0; kt < ksteps; ++kt) {
    const int k0 = kt * 64;
#pragma unroll
    for (int i = 0; i < 4; ++i) {
      const int q = i * 256 + t;
      const int row = q >> 3, c = q & 7;
      const int lo = row * 72 + c * 8;
      *(us8*)&As[lo] = *(const us8*)&Ah[(long)row * lda + k0 + c * 8];
      *(us8*)&Bs[lo] = *(const us8*)&Bh[(long)row * ldb + k0 + c * 8];
    }
    __syncthreads();
#pragma unroll
    for (int ks = 0; ks < 2; ++ks) {
      const int ko = ks * 32 + lk * 8;
      h8v ah[4], bh[4];
#pragma unroll
      for (int mi = 0; mi < 4; ++mi)
        ah[mi] = *(const h8v*)&As[(wm * 64 + mi * 16 + lr) * 72 + ko];
#pragma unroll
      for (int ni = 0; ni < 4; ++ni)
        bh[ni] = *(const h8v*)&Bs[(wn * 64 + ni * 16 + lr) * 72 + ko];
#pragma unroll
      for (int mi = 0; mi < 4; ++mi)
#pragma unroll
        for (int ni = 0; ni < 4; ++ni)
          acc[mi][ni] = __builtin_amdgcn_mfma_f32_16x16x32_f16(bh[ni], ah[mi], acc[mi][ni], 0, 0, 0);
    }
    __syncthreads();
  }

  // LDS-bounce epilogue: T[128][132]
  unsigned short* T = smem;
#pragma unroll
  for (int mi = 0; mi < 4; ++mi)
#pragma unroll
    for (int ni = 0; ni < 4; ++ni) {
      const int gm = wm * 64 + mi * 16 + lr;
      const int gn = wn * 64 + ni * 16 + lk * 4;
      us4 o;
#pragma unroll
      for (int r = 0; r < 4; ++r) o[r] = f2h(acc[mi][ni][r]);
      *(us4*)&T[gm * 132 + gn] = o;
    }
  __syncthreads();
#pragma unroll
  for (int i = 0; i < 8; ++i) {            // 128x128 / 256 thr = 8 us8
    const int q = i * 256 + t;
    const int row = q >> 4, c = q & 15;
    const us8 v = *(const us8*)&T[row * 132 + c * 8];
    *(us8*)&Cout[cOff + (long)row * ldc + c * 8] = v;
  }
}

// ------------------------------------------------------------------
// conv2: z2[b][o][p] = sum_c w2h[o,c]*y4T[b][p][c].  M=256 x N=64
// p-tile, K=128 (BK=64), 4 m-waves, acc[4][4].  LDS 46KB.
// ------------------------------------------------------------------
__global__ __launch_bounds__(256, 2)
void conv2_gemm(const unsigned short* __restrict__ w2h,
                const unsigned short* __restrict__ y4T,
                unsigned short* __restrict__ z2b)
{
  __shared__ __align__(16) unsigned short smem[23040];  // As 256*72 | Bs 64*72
  unsigned short* As = smem;                 // 18432
  unsigned short* Bs = smem + 18432;         // 4608

  const int t = threadIdx.x;
  const int lane = t & 63;
  const int wave = t >> 6;                   // 0..3 (all m)
  const int wm = wave;
  const int lr = lane & 15, lk = lane >> 4;
  const int b = blockIdx.z;
  const int nbase = blockIdx.x * 64;
  const unsigned short* Bh = y4T + (long)b * 4096 * 128 + (long)nbase * 128;

  f32x4 acc[4][4];
#pragma unroll
  for (int i = 0; i < 4; ++i)
#pragma unroll
    for (int j = 0; j < 4; ++j) acc[i][j] = (f32x4)0.0f;

  for (int kt = 0; kt < 2; ++kt) {
    const int k0 = kt * 64;
#pragma unroll
    for (int i = 0; i < 8; ++i) {           // A: 256 rows x 8 chunks
      const int q = i * 256 + t;
      const int row = q >> 3, c = q & 7;
      *(us8*)&As[row * 72 + c * 8] = *(const us8*)&w2h[(long)row * 128 + k0 + c * 8];
    }
#pragma unroll
    for (int i = 0; i < 2; ++i) {           // B: 64 rows x 8 chunks
      const int q = i * 256 + t;
      const int row = q >> 3, c = q & 7;
      *(us8*)&Bs[row * 72 + c * 8] = *(const us8*)&Bh[(long)row * 128 + k0 + c * 8];
    }
    __syncthreads();
#pragma unroll
    for (int ks = 0; ks < 2; ++ks) {
      const int ko = ks * 32 + lk * 8;
      h8v ah[4], bh[4];
#pragma unroll
      for (int mi = 0; mi < 4; ++mi)
        ah[mi] = *(const h8v*)&As[(wm * 64 + mi * 16 + lr) * 72 + ko];
#pragma unroll
      for (int ni = 0; ni < 4; ++ni)
        bh[ni] = *(const h8v*)&Bs[(ni * 16 + lr) * 72 + ko];
#pragma unroll
      for (int mi = 0; mi < 4; ++mi)
#pragma unroll
        for (int ni = 0; ni < 4; ++ni)
          acc[mi][ni] = __builtin_amdgcn_mfma_f32_16x16x32_f16(bh[ni], ah[mi], acc[mi][ni], 0, 0, 0);
    }
    __syncthreads();
  }

  // LDS-bounce epilogue: T[256][72] (aliases As)
  unsigned short* T = smem;
#pragma unroll
  for (int mi = 0; mi < 4; ++mi)
#pragma unroll
    for (int ni = 0; ni < 4; ++ni) {
      const int gm = wm * 64 + mi * 16 + lr;
      const int gn = ni * 16 + lk * 4;
      us4 o;
#pragma unroll
      for (int r = 0; r < 4; ++r) o[r] = f2h(acc[mi][ni][r]);
      *(us4*)&T[gm * 72 + gn] = o;
    }
  __syncthreads();
#pragma unroll
  for (int i = 0; i < 8; ++i) {            // 256x64 / 256 thr = 8 us8
    const int q = i * 256 + t;
    const int row = q >> 3, c = q & 7;
    const us8 v = *(const us8*)&T[row * 72 + c * 8];
    *(us8*)&z2b[((long)b * 256 + row) * 4096 + nbase + c * 8] = v;
  }
}

// ------------------------------------------------------------------
// normalize + relu + transpose g (zg fp16): -> gT [b][n][128]
// ------------------------------------------------------------------
__global__ __launch_bounds__(256)
void norm_transpose_g(const unsigned short* __restrict__ zg,
                      const float* __restrict__ stats,
                      unsigned short* __restrict__ gT)
{
  __shared__ unsigned short T[64 * 136];
  const int b = blockIdx.y, n0 = blockIdx.x * 64;
  const int t = threadIdx.x;
  const int c = t >> 1, part = t & 1;
  const int grow = b * 384 + 256 + c;
  const float rs = stats[grow * 2];
  const float nmrs = stats[grow * 2 + 1];
  const long off = ((long)b * 128 + c) * 4096 + n0 + part * 32;
#pragma unroll
  for (int j = 0; j < 4; ++j) {
    const us8 h = *(const us8*)&zg[off + j * 8];
#pragma unroll
    for (int e = 0; e < 8; ++e) {
      const float nv = fmaxf(__builtin_fmaf(h2f(h[e]), rs, nmrs), 0.f);
      T[(part * 32 + j * 8 + e) * 136 + c] = f2h(nv);
    }
  }
  __syncthreads();
  const int nl = t >> 2, q = t & 3;
  const long obase = ((long)b * 4096 + n0 + nl) * 128 + q * 32;
#pragma unroll
  for (int k = 0; k < 4; ++k) {
    us8 o;
#pragma unroll
    for (int e = 0; e < 8; ++e) o[e] = T[nl * 136 + q * 32 + k * 8 + e];
    *(us8*)&gT[obase + k * 8] = o;
  }
}

// ------------------------------------------------------------------
// softmax over j: 256 thr = 4 rows/block (wave per row), sums 32
// deterministic K-split partials, writes attn fp16
// ------------------------------------------------------------------
__global__ __launch_bounds__(256)
void softmax_attn(const float* __restrict__ fpart, unsigned short* __restrict__ attn)
{
  const int row = blockIdx.x * 4 + (threadIdx.x >> 6);  // b*128 + i
  const int b = row >> 7, i = row & 127;
  const int t = threadIdx.x & 63;
  float v0 = 0.f, v1 = 0.f;
#pragma unroll
  for (int kc = 0; kc < 32; ++kc) {
    const float* p = fpart + ((long)(b * 32 + kc)) * 16384 + i * 128;
    v0 += p[t];
    v1 += p[t + 64];
  }
  float mx = fmaxf(v0, v1);
  for (int o = 32; o > 0; o >>= 1) mx = fmaxf(mx, __shfl_xor(mx, o));
  const float e0 = __expf(v0 - mx), e1 = __expf(v1 - mx);
  float s = e0 + e1;
  for (int o = 32; o > 0; o >>= 1) s += __shfl_xor(s, o);
  const float inv = 1.f / s;
  attn[(long)row * 128 + t] = f2h(e0 * inv);
  attn[(long)row * 128 + t + 64] = f2h(e1 * inv);
}

// ------------------------------------------------------------------
// final: instance-norm of fp16 z2 + residual x -> fp32 d_out
// ------------------------------------------------------------------
__global__ __launch_bounds__(256)
void finalize(const unsigned short* __restrict__ z2b, const float* __restrict__ x,
              float* __restrict__ out)
{
  const int row = blockIdx.x;            // b*256 + o
  const long base = (long)row * 4096;
  const int t = threadIdx.x;
  float v[16];
  float s = 0.f, ss = 0.f;
#pragma unroll
  for (int h = 0; h < 2; ++h) {
    us8 u = *(const us8*)&z2b[base + t * 16 + h * 8];
#pragma unroll
    for (int e = 0; e < 8; ++e) {
      const float f = h2f(u[e]);
      v[h * 8 + e] = f;
      s += f; ss += f * f;
    }
  }
  __shared__ float r0[256], r1[256];
  r0[t] = s; r1[t] = ss;
  __syncthreads();
  for (int o = 128; o > 0; o >>= 1) {
    if (t < o) { r0[t] += r0[t + o]; r1[t] += r1[t + o]; }
    __syncthreads();
  }
  const float mean = r0[0] * (1.f / 4096.f);
  const float var = r1[0] * (1.f / 4096.f) - mean * mean;
  const float rs = rsqrtf(fmaxf(var, 0.f) + 1e-5f);
#pragma unroll
  for (int i = 0; i < 4; ++i) {
    f32x4 xr = *(const f32x4*)&x[base + t * 16 + i * 4];
    f32x4 o;
#pragma unroll
    for (int e = 0; e < 4; ++e) o[e] = (v[i * 4 + e] - mean) * rs + xr[e];
    *(f32x4*)&out[base + t * 16 + i * 4] = o;
  }
}

// ------------------------------------------------------------------
extern "C" void kernel_launch(void* const* d_in, const int* in_sizes, int n_in,
                              void* d_out, int out_size, void* d_ws, size_t ws_size,
                              hipStream_t stream)
{
  const float* x    = (const float*)d_in[0];
  const float* g_w  = (const float*)d_in[1];
  const float* th_w = (const float*)d_in[3];
  const float* ph_w = (const float*)d_in[5];
  const float* W_w  = (const float*)d_in[7];

  char* ws = (char*)d_ws;
  const size_t MB = 1024ull * 1024ull;
  if (ws_size < 186 * MB) return;

  // region map:
  // [0,64)    zr (raw z fp32, theta/phi 256 rows/b) -> z2b reuses [0,32)
  // [64,80)   zg (raw z fp16, g 128 rows/b)
  // [80,112)  fpart
  // [112,113) attn
  // [113,129) gT
  // [129,145) y4T
  // [145,149) partials
  // [149,150) stats
  // [150,151) weights
  float*          zr       = (float*)(ws);
  unsigned short* zg       = (unsigned short*)(ws + 64 * MB);
  float*          fpart    = (float*)(ws + 80 * MB);
  unsigned short* attn     = (unsigned short*)(ws + 112 * MB);
  unsigned short* gT       = (unsigned short*)(ws + 113 * MB);
  unsigned short* y4T      = (unsigned short*)(ws + 129 * MB);
  unsigned short* z2b      = (unsigned short*)(ws);             // reuse zr
  float*          partials = (float*)(ws + 145 * MB);
  float*          stats    = (float*)(ws + 149 * MB);
  unsigned short* wall_h   = (unsigned short*)(ws + 150 * MB);
  unsigned short* wall_l   = (unsigned short*)(ws + 150 * MB + 256 * 1024);
  unsigned short* w2h      = (unsigned short*)(ws + 150 * MB + 512 * 1024);

  // 1) weight prep
  prep_weights<<<dim3(384), 256, 0, stream>>>(g_w, th_w, ph_w, W_w, wall_h, wall_l, w2h);

  // 2) projection (BK=32 full-dbuf single-barrier pipeline)
  proj_gemm<<<dim3(32, 1, 16), 512, 0, stream>>>(wall_h, wall_l, x, zr, zg, partials);

  // 3) instance-norm stats
  stats_reduce<<<dim3(24), 256, 0, stream>>>(partials, stats);

  // 4) g: normalize+relu+transpose -> gT[b][n][128]
  norm_transpose_g<<<dim3(64, 16), 256, 0, stream>>>(zg, stats, gT);

  // 5) f = theta.phi^T (3-pass split from fp32 zr, normalize fused)
  fgemm_norm<<<dim3(1, 1, 512), 256, 0, stream>>>(zr, stats, fpart);

  // 6) softmax rows -> attn fp16
  softmax_attn<<<dim3(512), 256, 0, stream>>>(fpart, attn);

  // 7) y = attn . g, written scrambled-transposed y4T[b][p][c]
  gemm_y<<<dim3(1, 1, 512), 256, 0, stream>>>(
      attn, gT, y4T,
      128, 4096, 128, 2, 32,
      0, 16384, 128, (long)4096 * 128, 16384, (long)4096 * 128);

  // 8) final conv -> fp16 z2b [b][o][p]  (overwrites zr after fgemm done)
  conv2_gemm<<<dim3(64, 1, 16), 256, 0, stream>>>(w2h, y4T, z2b);

  // 9) instance-norm of z2 + residual x -> d_out fp32
  finalize<<<dim3(4096), 256, 0, stream>>>(z2b, x, (float*)d_out);
}

// Round 16
// 147.044 us; speedup vs baseline: 1.0379x; 1.0379x over previous
//
#include <hip/hip_runtime.h>

#define DEVINL __device__ __forceinline__

typedef __attribute__((ext_vector_type(8))) _Float16 h8v;         // 8 fp16 (MFMA operand)
typedef __attribute__((ext_vector_type(4))) float f32x4;
typedef __attribute__((ext_vector_type(8))) unsigned short us8;
typedef __attribute__((ext_vector_type(4))) unsigned short us4;

DEVINL unsigned short f2h(float f) {                  // fp32 -> fp16 bits (RTE)
  return __builtin_bit_cast(unsigned short, (_Float16)f);
}
DEVINL float h2f(unsigned short u) {
  return (float)__builtin_bit_cast(_Float16, u);
}

// ------------------------------------------------------------------
// weights (row-major): wall_h rows [0..127]=theta, [128..255]=phi,
// [256..383]=g; wall_l = fp16 residual rows 0..255; W2 fp16 [256][128]
// ------------------------------------------------------------------
__global__ __launch_bounds__(256)
void prep_weights(const float* __restrict__ g_w, const float* __restrict__ th_w,
                  const float* __restrict__ ph_w, const float* __restrict__ W_w,
                  unsigned short* __restrict__ wall_h, unsigned short* __restrict__ wall_l,
                  unsigned short* __restrict__ w2h)
{
  const int i = blockIdx.x * 256 + threadIdx.x;  // [0, 98304)
  float v;
  if (i < 32768) v = th_w[i];
  else if (i < 65536) v = ph_w[i - 32768];
  else v = g_w[i - 65536];
  const unsigned short h = f2h(v);
  wall_h[i] = h;
  if (i < 65536) wall_l[i] = f2h(v - h2f(h));
  if (i < 32768) w2h[i] = f2h(W_w[i]);
}

// ------------------------------------------------------------------
// Fused projection, tile = M384 x N128, BK=64, LDS-A (r13 structure —
// the measured optimum after six pipelining variants all regressed).
// theta/phi rows: 3-pass fp16 hi/lo split; g rows: 1-pass.
// Epilogue: global stores issued BEFORE the stats LDS-reduction so the
// store drain overlaps the reduce+barrier (no hazard: stores touch no
// LDS; sbuf aliases As which is dead after the loop).
// ------------------------------------------------------------------
__global__ __launch_bounds__(512, 2)
void proj_gemm(const unsigned short* __restrict__ wall_h,
               const unsigned short* __restrict__ wall_l,
               const float* __restrict__ x,
               float* __restrict__ zr, unsigned short* __restrict__ zg,
               float* __restrict__ partials)
{
  __shared__ __align__(16) unsigned short smem[64512];   // 129KB
  unsigned short* As_h = smem;                 // 384*72 = 27648
  unsigned short* As_l = smem + 27648;         // 256*72 = 18432
  unsigned short* Bs_h = smem + 46080;         // 128*72 = 9216
  unsigned short* Bs_l = smem + 55296;         // 128*72 = 9216

  const int t = threadIdx.x;
  const int lane = t & 63;
  const int wave = t >> 6;                 // 0..7
  const int wm = wave >> 1, wn = wave & 1; // 4 x 2
  const int lr = lane & 15, lk = lane >> 4;
  const int b = blockIdx.z;
  const int bx = blockIdx.x;
  const int nbase = bx * 128;
  const float* xs = x + (long)b * 256 * 4096;

  f32x4 acc[6][4];
#pragma unroll
  for (int i = 0; i < 6; ++i)
#pragma unroll
    for (int j = 0; j < 4; ++j) acc[i][j] = (f32x4)0.0f;

  const int nl = t & 127, cg = t >> 7;     // B staging: lane-per-n, 4 c-groups x 16

  for (int kt = 0; kt < 4; ++kt) {
    const int k0 = kt * 64;
    // A hi: 384 rows x 8 us8-chunks = 3072 -> 6/thread
#pragma unroll
    for (int i = 0; i < 6; ++i) {
      const int q = i * 512 + t;
      const int row = q >> 3, c = q & 7;
      *(us8*)&As_h[row * 72 + c * 8] = *(const us8*)&wall_h[(long)row * 256 + k0 + c * 8];
    }
    // A lo: 256 rows x 8 = 2048 -> 4/thread
#pragma unroll
    for (int i = 0; i < 4; ++i) {
      const int q = i * 512 + t;
      const int row = q >> 3, c = q & 7;
      *(us8*)&As_l[row * 72 + c * 8] = *(const us8*)&wall_l[(long)row * 256 + k0 + c * 8];
    }
    // B from fp32 x[c][n]: 64 c x 128 n; convert + hi/lo split in regs
#pragma unroll
    for (int hp = 0; hp < 2; ++hp) {
      float xv[8];
#pragma unroll
      for (int i = 0; i < 8; ++i)
        xv[i] = xs[(long)(k0 + cg * 16 + hp * 8 + i) * 4096 + nbase + nl];
      us8 h8, l8;
#pragma unroll
      for (int e = 0; e < 8; ++e) {
        const unsigned short hb = f2h(xv[e]);
        h8[e] = hb;
        l8[e] = f2h(xv[e] - h2f(hb));
      }
      *(us8*)&Bs_h[nl * 72 + cg * 16 + hp * 8] = h8;
      *(us8*)&Bs_l[nl * 72 + cg * 16 + hp * 8] = l8;
    }
    __syncthreads();

#pragma unroll
    for (int ks = 0; ks < 2; ++ks) {
      const int ko = ks * 32 + lk * 8;
      h8v bh[4], bl[4];
#pragma unroll
      for (int ni = 0; ni < 4; ++ni) {
        const int r = (wn * 64 + ni * 16 + lr) * 72 + ko;
        bh[ni] = *(const h8v*)&Bs_h[r];
        bl[ni] = *(const h8v*)&Bs_l[r];
      }
#pragma unroll
      for (int mi = 0; mi < 6; ++mi) {
        const int fr = mi * 4 + wm;        // frag row block 0..23
        const h8v ah = *(const h8v*)&As_h[(fr * 16 + lr) * 72 + ko];
        if (fr < 16) {                      // theta/phi: 3-pass split
          const h8v al = *(const h8v*)&As_l[(fr * 16 + lr) * 72 + ko];
#pragma unroll
          for (int ni = 0; ni < 4; ++ni) {
            acc[mi][ni] = __builtin_amdgcn_mfma_f32_16x16x32_f16(bh[ni], ah, acc[mi][ni], 0, 0, 0);
            acc[mi][ni] = __builtin_amdgcn_mfma_f32_16x16x32_f16(bl[ni], ah, acc[mi][ni], 0, 0, 0);
            acc[mi][ni] = __builtin_amdgcn_mfma_f32_16x16x32_f16(bh[ni], al, acc[mi][ni], 0, 0, 0);
          }
        } else {                            // g: 1-pass
#pragma unroll
          for (int ni = 0; ni < 4; ++ni)
            acc[mi][ni] = __builtin_amdgcn_mfma_f32_16x16x32_f16(bh[ni], ah, acc[mi][ni], 0, 0, 0);
        }
      }
    }
    __syncthreads();
  }

  // ---- C write FIRST (r3-style direct): theta/phi -> fp32 zr; g -> fp16 zg.
  //      Stores drain under the stats reduction below (no LDS dependency). ----
#pragma unroll
  for (int mi = 0; mi < 6; ++mi)
#pragma unroll
    for (int ni = 0; ni < 4; ++ni) {
      const int gm = (mi * 4 + wm) * 16 + lr;
      const int gn = nbase + wn * 64 + ni * 16 + lk * 4;
      if (mi < 4) {
        *(f32x4*)&zr[((long)b * 256 + gm) * 4096 + gn] = acc[mi][ni];
      } else {
        us4 hv;
#pragma unroll
        for (int r = 0; r < 4; ++r) hv[r] = f2h(acc[mi][ni][r]);
        *(us4*)&zg[((long)b * 128 + (gm - 256)) * 4096 + gn] = hv;
      }
    }

  // ---- partial stats: per row m, sum over this block's 128 n ----
  float* sbuf = (float*)smem;              // 6144 floats = 24KB alias (As dead)
#pragma unroll
  for (int mi = 0; mi < 6; ++mi) {
    float s = 0.f, ss = 0.f;
#pragma unroll
    for (int ni = 0; ni < 4; ++ni)
#pragma unroll
      for (int r = 0; r < 4; ++r) {
        const float v = acc[mi][ni][r];
        s += v; ss += v * v;
      }
    const int fr = mi * 4 + wm;
    const int slot = ((fr * 16 + lr) * 8 + (wn * 4 + lk)) * 2;
    sbuf[slot] = s; sbuf[slot + 1] = ss;
  }
  __syncthreads();
  if (t < 384) {
    float s = 0.f, ss = 0.f;
#pragma unroll
    for (int w = 0; w < 8; ++w) {
      s += sbuf[(t * 8 + w) * 2];
      ss += sbuf[(t * 8 + w) * 2 + 1];
    }
    const long pidx = ((long)bx * 6144 + b * 384 + t) * 2;
    partials[pidx] = s; partials[pidx + 1] = ss;
  }
}

// ------------------------------------------------------------------
// reduce 32 partial (s,ss) per row -> stats[row] = {rs, -mean*rs}
// ------------------------------------------------------------------
__global__ __launch_bounds__(256)
void stats_reduce(const float* __restrict__ partials, float* __restrict__ stats)
{
  const int row = blockIdx.x * 256 + threadIdx.x;   // [0, 6144)
  float s = 0.f, ss = 0.f;
#pragma unroll
  for (int k = 0; k < 32; ++k) {
    s += partials[((long)k * 6144 + row) * 2];
    ss += partials[((long)k * 6144 + row) * 2 + 1];
  }
  const float mean = s * (1.f / 4096.f);
  const float var = ss * (1.f / 4096.f) - mean * mean;
  const float rs = rsqrtf(fmaxf(var, 0.f) + 1e-5f);
  stats[row * 2] = rs;
  stats[row * 2 + 1] = -mean * rs;
}

// ------------------------------------------------------------------
// f = theta.phi^T, 3-pass fp16 split; staging reads RAW FP32 zr,
// applies normalize+relu, splits hi/lo to LDS.  Tile 128x128, BK=64,
// K-slice 128 per z1 (32 chunks).
// ------------------------------------------------------------------
__global__ __launch_bounds__(256, 2)
void fgemm_norm(const float* __restrict__ zr,
                const float* __restrict__ stats, float* __restrict__ fpart)
{
  __shared__ __align__(16) unsigned short As_h[128 * 72];
  __shared__ __align__(16) unsigned short As_l[128 * 72];
  __shared__ __align__(16) unsigned short Bs_h[128 * 72];
  __shared__ __align__(16) unsigned short Bs_l[128 * 72];

  const int t = threadIdx.x;
  const int lane = t & 63;
  const int wave = t >> 6;
  const int wm = wave >> 1, wn = wave & 1;
  const int lr = lane & 15, lk = lane >> 4;
  const int zb = blockIdx.z >> 5, z1 = blockIdx.z & 31;
  const int koff = z1 * 128;

  f32x4 acc[4][4];
#pragma unroll
  for (int i = 0; i < 4; ++i)
#pragma unroll
    for (int j = 0; j < 4; ++j) acc[i][j] = (f32x4)0.0f;

  for (int kt = 0; kt < 2; ++kt) {
    const int k0 = koff + kt * 64;
#pragma unroll
    for (int i = 0; i < 4; ++i) {
      const int q = i * 256 + t;
      const int row = q >> 3, c = q & 7;
      // A = theta (zr rows 0..127), B = phi (zr rows 128..255)
#pragma unroll
      for (int op = 0; op < 2; ++op) {
        const int zrow = op * 128 + row;
        const float* src = zr + ((long)zb * 256 + zrow) * 4096 + k0 + c * 8;
        const f32x4 v0 = *(const f32x4*)&src[0];
        const f32x4 v1 = *(const f32x4*)&src[4];
        const int srow = zb * 384 + zrow;
        const float rs = stats[srow * 2];
        const float nmrs = stats[srow * 2 + 1];
        us8 oh, ol;
#pragma unroll
        for (int e = 0; e < 8; ++e) {
          const float v = (e < 4) ? v0[e] : v1[e - 4];
          const float nv = fmaxf(__builtin_fmaf(v, rs, nmrs), 0.f);
          const unsigned short hb = f2h(nv);
          oh[e] = hb;
          ol[e] = f2h(nv - h2f(hb));
        }
        unsigned short* dh = op ? Bs_h : As_h;
        unsigned short* dl = op ? Bs_l : As_l;
        *(us8*)&dh[row * 72 + c * 8] = oh;
        *(us8*)&dl[row * 72 + c * 8] = ol;
      }
    }
    __syncthreads();
#pragma unroll
    for (int ks = 0; ks < 2; ++ks) {
      const int ko = ks * 32 + lk * 8;
      h8v ah[4], bh[4], al[4], bl[4];
#pragma unroll
      for (int mi = 0; mi < 4; ++mi) {
        const int r = (wm * 64 + mi * 16 + lr) * 72 + ko;
        ah[mi] = *(const h8v*)&As_h[r];
        al[mi] = *(const h8v*)&As_l[r];
      }
#pragma unroll
      for (int ni = 0; ni < 4; ++ni) {
        const int r = (wn * 64 + ni * 16 + lr) * 72 + ko;
        bh[ni] = *(const h8v*)&Bs_h[r];
        bl[ni] = *(const h8v*)&Bs_l[r];
      }
#pragma unroll
      for (int mi = 0; mi < 4; ++mi)
#pragma unroll
        for (int ni = 0; ni < 4; ++ni) {
          acc[mi][ni] = __builtin_amdgcn_mfma_f32_16x16x32_f16(bh[ni], ah[mi], acc[mi][ni], 0, 0, 0);
          acc[mi][ni] = __builtin_amdgcn_mfma_f32_16x16x32_f16(bl[ni], ah[mi], acc[mi][ni], 0, 0, 0);
          acc[mi][ni] = __builtin_amdgcn_mfma_f32_16x16x32_f16(bh[ni], al[mi], acc[mi][ni], 0, 0, 0);
        }
    }
    __syncthreads();
  }

  const long cOff = ((long)zb * 32 + z1) * 16384;
#pragma unroll
  for (int mi = 0; mi < 4; ++mi)
#pragma unroll
    for (int ni = 0; ni < 4; ++ni) {
      const int gm = wm * 64 + mi * 16 + lr;
      const int gn = wn * 64 + ni * 16 + lk * 4;
      *(f32x4*)&fpart[cOff + (long)gm * 128 + gn] = acc[mi][ni];
    }
}

// ------------------------------------------------------------------
// y GEMM: tile 128x128, BK=64, fp16, LDS-bounce coalesced epilogue.
// ------------------------------------------------------------------
__global__ __launch_bounds__(256, 2)
void gemm_y(const unsigned short* __restrict__ Ah0, const unsigned short* __restrict__ Bh0,
            unsigned short* __restrict__ Cout,
            int lda, int ldb, int ldc, int ksteps, int z1count,
            long aS1, long aS2, long bS1, long bS2, long cS1, long cS2)
{
  __shared__ __align__(16) unsigned short smem[18432];   // As|Bs, reused as T
  unsigned short* As = smem;                 // 128*72
  unsigned short* Bs = smem + 9216;          // 128*72

  const int t = threadIdx.x;
  const int lane = t & 63;
  const int wave = t >> 6;
  const int wm = wave >> 1, wn = wave & 1;
  const int lr = lane & 15, lk = lane >> 4;

  const int z = blockIdx.z;
  const int zb = z / z1count, z1 = z - zb * z1count;
  const unsigned short* Ah = Ah0 + zb * aS2 + z1 * aS1;
  const unsigned short* Bh = Bh0 + zb * bS2 + z1 * bS1;
  const long cOff = zb * cS2 + z1 * cS1;

  f32x4 acc[4][4];
#pragma unroll
  for (int i = 0; i < 4; ++i)
#pragma unroll
    for (int j = 0; j < 4; ++j) acc[i][j] = (f32x4)0.0f;

  for (int kt = 0; kt < ksteps; ++kt) {
    const int k0 = kt * 64;
#pragma unroll
    for (int i = 0; i < 4; ++i) {
      const int q = i * 256 + t;
      const int row = q >> 3, c = q & 7;
      const int lo = row * 72 + c * 8;
      *(us8*)&As[lo] = *(const us8*)&Ah[(long)row * lda + k0 + c * 8];
      *(us8*)&Bs[lo] = *(const us8*)&Bh[(long)row * ldb + k0 + c * 8];
    }
    __syncthreads();
#pragma unroll
    for (int ks = 0; ks < 2; ++ks) {
      const int ko = ks * 32 + lk * 8;
      h8v ah[4], bh[4];
#pragma unroll
      for (int mi = 0; mi < 4; ++mi)
        ah[mi] = *(const h8v*)&As[(wm * 64 + mi * 16 + lr) * 72 + ko];
#pragma unroll
      for (int ni = 0; ni < 4; ++ni)
        bh[ni] = *(const h8v*)&Bs[(wn * 64 + ni * 16 + lr) * 72 + ko];
#pragma unroll
      for (int mi = 0; mi < 4; ++mi)
#pragma unroll
        for (int ni = 0; ni < 4; ++ni)
          acc[mi][ni] = __builtin_amdgcn_mfma_f32_16x16x32_f16(bh[ni], ah[mi], acc[mi][ni], 0, 0, 0);
    }
    __syncthreads();
  }

  // LDS-bounce epilogue: T[128][132]
  unsigned short* T = smem;
#pragma unroll
  for (int mi = 0; mi < 4; ++mi)
#pragma unroll
    for (int ni = 0; ni < 4; ++ni) {
      const int gm = wm * 64 + mi * 16 + lr;
      const int gn = wn * 64 + ni * 16 + lk * 4;
      us4 o;
#pragma unroll
      for (int r = 0; r < 4; ++r) o[r] = f2h(acc[mi][ni][r]);
      *(us4*)&T[gm * 132 + gn] = o;
    }
  __syncthreads();
#pragma unroll
  for (int i = 0; i < 8; ++i) {            // 128x128 / 256 thr = 8 us8
    const int q = i * 256 + t;
    const int row = q >> 4, c = q & 15;
    const us8 v = *(const us8*)&T[row * 132 + c * 8];
    *(us8*)&Cout[cOff + (long)row * ldc + c * 8] = v;
  }
}

// ------------------------------------------------------------------
// conv2: z2[b][o][p] = sum_c w2h[o,c]*y4T[b][p][c].  M=256 x N=64
// p-tile, K=128 (BK=64), 4 m-waves, acc[4][4].  LDS 46KB.
// ------------------------------------------------------------------
__global__ __launch_bounds__(256, 2)
void conv2_gemm(const unsigned short* __restrict__ w2h,
                const unsigned short* __restrict__ y4T,
                unsigned short* __restrict__ z2b)
{
  __shared__ __align__(16) unsigned short smem[23040];  // As 256*72 | Bs 64*72
  unsigned short* As = smem;                 // 18432
  unsigned short* Bs = smem + 18432;         // 4608

  const int t = threadIdx.x;
  const int lane = t & 63;
  const int wave = t >> 6;                   // 0..3 (all m)
  const int wm = wave;
  const int lr = lane & 15, lk = lane >> 4;
  const int b = blockIdx.z;
  const int nbase = blockIdx.x * 64;
  const unsigned short* Bh = y4T + (long)b * 4096 * 128 + (long)nbase * 128;

  f32x4 acc[4][4];
#pragma unroll
  for (int i = 0; i < 4; ++i)
#pragma unroll
    for (int j = 0; j < 4; ++j) acc[i][j] = (f32x4)0.0f;

  for (int kt = 0; kt < 2; ++kt) {
    const int k0 = kt * 64;
#pragma unroll
    for (int i = 0; i < 8; ++i) {           // A: 256 rows x 8 chunks
      const int q = i * 256 + t;
      const int row = q >> 3, c = q & 7;
      *(us8*)&As[row * 72 + c * 8] = *(const us8*)&w2h[(long)row * 128 + k0 + c * 8];
    }
#pragma unroll
    for (int i = 0; i < 2; ++i) {           // B: 64 rows x 8 chunks
      const int q = i * 256 + t;
      const int row = q >> 3, c = q & 7;
      *(us8*)&Bs[row * 72 + c * 8] = *(const us8*)&Bh[(long)row * 128 + k0 + c * 8];
    }
    __syncthreads();
#pragma unroll
    for (int ks = 0; ks < 2; ++ks) {
      const int ko = ks * 32 + lk * 8;
      h8v ah[4], bh[4];
#pragma unroll
      for (int mi = 0; mi < 4; ++mi)
        ah[mi] = *(const h8v*)&As[(wm * 64 + mi * 16 + lr) * 72 + ko];
#pragma unroll
      for (int ni = 0; ni < 4; ++ni)
        bh[ni] = *(const h8v*)&Bs[(ni * 16 + lr) * 72 + ko];
#pragma unroll
      for (int mi = 0; mi < 4; ++mi)
#pragma unroll
        for (int ni = 0; ni < 4; ++ni)
          acc[mi][ni] = __builtin_amdgcn_mfma_f32_16x16x32_f16(bh[ni], ah[mi], acc[mi][ni], 0, 0, 0);
    }
    __syncthreads();
  }

  // LDS-bounce epilogue: T[256][72] (aliases As)
  unsigned short* T = smem;
#pragma unroll
  for (int mi = 0; mi < 4; ++mi)
#pragma unroll
    for (int ni = 0; ni < 4; ++ni) {
      const int gm = wm * 64 + mi * 16 + lr;
      const int gn = ni * 16 + lk * 4;
      us4 o;
#pragma unroll
      for (int r = 0; r < 4; ++r) o[r] = f2h(acc[mi][ni][r]);
      *(us4*)&T[gm * 72 + gn] = o;
    }
  __syncthreads();
#pragma unroll
  for (int i = 0; i < 8; ++i) {            // 256x64 / 256 thr = 8 us8
    const int q = i * 256 + t;
    const int row = q >> 3, c = q & 7;
    const us8 v = *(const us8*)&T[row * 72 + c * 8];
    *(us8*)&z2b[((long)b * 256 + row) * 4096 + nbase + c * 8] = v;
  }
}

// ------------------------------------------------------------------
// normalize + relu + transpose g (zg fp16): -> gT [b][n][128]
// ------------------------------------------------------------------
__global__ __launch_bounds__(256)
void norm_transpose_g(const unsigned short* __restrict__ zg,
                      const float* __restrict__ stats,
                      unsigned short* __restrict__ gT)
{
  __shared__ unsigned short T[64 * 136];
  const int b = blockIdx.y, n0 = blockIdx.x * 64;
  const int t = threadIdx.x;
  const int c = t >> 1, part = t & 1;
  const int grow = b * 384 + 256 + c;
  const float rs = stats[grow * 2];
  const float nmrs = stats[grow * 2 + 1];
  const long off = ((long)b * 128 + c) * 4096 + n0 + part * 32;
#pragma unroll
  for (int j = 0; j < 4; ++j) {
    const us8 h = *(const us8*)&zg[off + j * 8];
#pragma unroll
    for (int e = 0; e < 8; ++e) {
      const float nv = fmaxf(__builtin_fmaf(h2f(h[e]), rs, nmrs), 0.f);
      T[(part * 32 + j * 8 + e) * 136 + c] = f2h(nv);
    }
  }
  __syncthreads();
  const int nl = t >> 2, q = t & 3;
  const long obase = ((long)b * 4096 + n0 + nl) * 128 + q * 32;
#pragma unroll
  for (int k = 0; k < 4; ++k) {
    us8 o;
#pragma unroll
    for (int e = 0; e < 8; ++e) o[e] = T[nl * 136 + q * 32 + k * 8 + e];
    *(us8*)&gT[obase + k * 8] = o;
  }
}

// ------------------------------------------------------------------
// softmax over j: 256 thr = 4 rows/block (wave per row), sums 32
// deterministic K-split partials, writes attn fp16
// ------------------------------------------------------------------
__global__ __launch_bounds__(256)
void softmax_attn(const float* __restrict__ fpart, unsigned short* __restrict__ attn)
{
  const int row = blockIdx.x * 4 + (threadIdx.x >> 6);  // b*128 + i
  const int b = row >> 7, i = row & 127;
  const int t = threadIdx.x & 63;
  float v0 = 0.f, v1 = 0.f;
#pragma unroll
  for (int kc = 0; kc < 32; ++kc) {
    const float* p = fpart + ((long)(b * 32 + kc)) * 16384 + i * 128;
    v0 += p[t];
    v1 += p[t + 64];
  }
  float mx = fmaxf(v0, v1);
  for (int o = 32; o > 0; o >>= 1) mx = fmaxf(mx, __shfl_xor(mx, o));
  const float e0 = __expf(v0 - mx), e1 = __expf(v1 - mx);
  float s = e0 + e1;
  for (int o = 32; o > 0; o >>= 1) s += __shfl_xor(s, o);
  const float inv = 1.f / s;
  attn[(long)row * 128 + t] = f2h(e0 * inv);
  attn[(long)row * 128 + t + 64] = f2h(e1 * inv);
}

// ------------------------------------------------------------------
// final: instance-norm of fp16 z2 + residual x -> fp32 d_out
// ------------------------------------------------------------------
__global__ __launch_bounds__(256)
void finalize(const unsigned short* __restrict__ z2b, const float* __restrict__ x,
              float* __restrict__ out)
{
  const int row = blockIdx.x;            // b*256 + o
  const long base = (long)row * 4096;
  const int t = threadIdx.x;
  float v[16];
  float s = 0.f, ss = 0.f;
#pragma unroll
  for (int h = 0; h < 2; ++h) {
    us8 u = *(const us8*)&z2b[base + t * 16 + h * 8];
#pragma unroll
    for (int e = 0; e < 8; ++e) {
      const float f = h2f(u[e]);
      v[h * 8 + e] = f;
      s += f; ss += f * f;
    }
  }
  __shared__ float r0[256], r1[256];
  r0[t] = s; r1[t] = ss;
  __syncthreads();
  for (int o = 128; o > 0; o >>= 1) {
    if (t < o) { r0[t] += r0[t + o]; r1[t] += r1[t + o]; }
    __syncthreads();
  }
  const float mean = r0[0] * (1.f / 4096.f);
  const float var = r1[0] * (1.f / 4096.f) - mean * mean;
  const float rs = rsqrtf(fmaxf(var, 0.f) + 1e-5f);
#pragma unroll
  for (int i = 0; i < 4; ++i) {
    f32x4 xr = *(const f32x4*)&x[base + t * 16 + i * 4];
    f32x4 o;
#pragma unroll
    for (int e = 0; e < 4; ++e) o[e] = (v[i * 4 + e] - mean) * rs + xr[e];
    *(f32x4*)&out[base + t * 16 + i * 4] = o;
  }
}

// ------------------------------------------------------------------
extern "C" void kernel_launch(void* const* d_in, const int* in_sizes, int n_in,
                              void* d_out, int out_size, void* d_ws, size_t ws_size,
                              hipStream_t stream)
{
  const float* x    = (const float*)d_in[0];
  const float* g_w  = (const float*)d_in[1];
  const float* th_w = (const float*)d_in[3];
  const float* ph_w = (const float*)d_in[5];
  const float* W_w  = (const float*)d_in[7];

  char* ws = (char*)d_ws;
  const size_t MB = 1024ull * 1024ull;
  if (ws_size < 186 * MB) return;

  // region map:
  // [0,64)    zr (raw z fp32, theta/phi 256 rows/b) -> z2b reuses [0,32)
  // [64,80)   zg (raw z fp16, g 128 rows/b)
  // [80,112)  fpart
  // [112,113) attn
  // [113,129) gT
  // [129,145) y4T
  // [145,149) partials
  // [149,150) stats
  // [150,151) weights
  float*          zr       = (float*)(ws);
  unsigned short* zg       = (unsigned short*)(ws + 64 * MB);
  float*          fpart    = (float*)(ws + 80 * MB);
  unsigned short* attn     = (unsigned short*)(ws + 112 * MB);
  unsigned short* gT       = (unsigned short*)(ws + 113 * MB);
  unsigned short* y4T      = (unsigned short*)(ws + 129 * MB);
  unsigned short* z2b      = (unsigned short*)(ws);             // reuse zr
  float*          partials = (float*)(ws + 145 * MB);
  float*          stats    = (float*)(ws + 149 * MB);
  unsigned short* wall_h   = (unsigned short*)(ws + 150 * MB);
  unsigned short* wall_l   = (unsigned short*)(ws + 150 * MB + 256 * 1024);
  unsigned short* w2h      = (unsigned short*)(ws + 150 * MB + 512 * 1024);

  // 1) weight prep
  prep_weights<<<dim3(384), 256, 0, stream>>>(g_w, th_w, ph_w, W_w, wall_h, wall_l, w2h);

  // 2) projection (r13 loop; stores-first epilogue: fp32 zr + fp16 zg + partials)
  proj_gemm<<<dim3(32, 1, 16), 512, 0, stream>>>(wall_h, wall_l, x, zr, zg, partials);

  // 3) instance-norm stats
  stats_reduce<<<dim3(24), 256, 0, stream>>>(partials, stats);

  // 4) g: normalize+relu+transpose -> gT[b][n][128]
  norm_transpose_g<<<dim3(64, 16), 256, 0, stream>>>(zg, stats, gT);

  // 5) f = theta.phi^T (3-pass split from fp32 zr, normalize fused)
  fgemm_norm<<<dim3(1, 1, 512), 256, 0, stream>>>(zr, stats, fpart);

  // 6) softmax rows -> attn fp16
  softmax_attn<<<dim3(512), 256, 0, stream>>>(fpart, attn);

  // 7) y = attn . g, written scrambled-transposed y4T[b][p][c]
  gemm_y<<<dim3(1, 1, 512), 256, 0, stream>>>(
      attn, gT, y4T,
      128, 4096, 128, 2, 32,
      0, 16384, 128, (long)4096 * 128, 16384, (long)4096 * 128);

  // 8) final conv -> fp16 z2b [b][o][p]  (overwrites zr after fgemm done)
  conv2_gemm<<<dim3(64, 1, 16), 256, 0, stream>>>(w2h, y4T, z2b);

  // 9) instance-norm of z2 + residual x -> d_out fp32
  finalize<<<dim3(4096), 256, 0, stream>>>(z2b, x, (float*)d_out);
}